// Round 12
// baseline (330.128 us; speedup 1.0000x reference)
//
#include <hip/hip_runtime.h>
#include <hip/hip_bf16.h>

#define N_NODES  20000
#define N_EDGES  320000
#define E_TOT    (N_EDGES + N_NODES)   /* 340000 incl. self loops */
#define N_GRAPHS 512
#define H1 10
#define C1 78
#define F1 780                          /* H1*C1 */
#define C2 100
#define NEG_SLOPE 0.2f
#define K1PAD 96                        /* layer-1 K (78) padded to 3x32 */
#define K2PAD 800                       /* layer-2 K (780) padded to 25x32 */
#define AP1 104                         /* LDS row stride (bf16) for W1/xb staging */
#define AP2 40                          /* LDS row stride for W2 staging */
#define HAP 808                         /* LDS row stride for ha (800 + 8 pad) */
#define HP 12                           /* padded head stride for asb/adb */

typedef short bf16x8 __attribute__((ext_vector_type(8)));
typedef float f32x4 __attribute__((ext_vector_type(4)));
typedef _Float16 half2v __attribute__((ext_vector_type(2)));
typedef unsigned short ushort_t;

__device__ __forceinline__ float bf_lo(unsigned int u) { return __uint_as_float(u << 16); }
__device__ __forceinline__ float bf_hi(unsigned int u) { return __uint_as_float(u & 0xFFFF0000u); }
__device__ __forceinline__ ushort_t f2b(float v) {
  __hip_bfloat16 b = __float2bfloat16(v);   /* RNE */
  return *reinterpret_cast<ushort_t*>(&b);
}
__device__ __forceinline__ ushort_t f2h(float v) {
  _Float16 h = (_Float16)v;                 /* RNE */
  return *reinterpret_cast<ushort_t*>(&h);
}
__device__ __forceinline__ float lrelu(float v) { return (v > 0.f) ? v : NEG_SLOPE * v; }
__device__ __forceinline__ float dot2h(unsigned int a, unsigned int b, float c) {
  union { unsigned int u; half2v v; } A, B;
  A.u = a; B.u = b;
  return __builtin_amdgcn_fdot2(A.v, B.v, c, false);
}

/* ---------------- fused count + prep ----------------
   blocks [0, NB_CNT): edge-degree count
   blocks [NB_CNT, ..): Vs/Vd + W1t + W2t + x->fp16 */

#define PR0 (2 * H1 * C1)
#define PR1 (H1 * 80 * K1PAD)
#define PR2 (112 * K2PAD)
#define PR4 (N_NODES * 40)
#define PRT (PR0 + PR1 + PR2 + PR4)
#define NB_CNT ((E_TOT + 255) / 256)
#define NB_PREP ((PRT + 255) / 256)

__global__ void k_cntprep(const int* __restrict__ ei,
                          const float* __restrict__ W1, const float* __restrict__ a_src,
                          const float* __restrict__ a_dst, const float* __restrict__ W2,
                          const float* __restrict__ x,
                          int* __restrict__ cnt,
                          float* __restrict__ Vs, float* __restrict__ Vd,
                          ushort_t* __restrict__ W1t, ushort_t* __restrict__ W2t,
                          ushort_t* __restrict__ xhf) {
  if (blockIdx.x < NB_CNT) {
    int e = blockIdx.x * 256 + threadIdx.x;
    if (e >= E_TOT) return;
    int dst = (e < N_EDGES) ? ei[N_EDGES + e] : (e - N_EDGES);
    atomicAdd(&cnt[dst], 1);
    return;
  }
  int t = (blockIdx.x - NB_CNT) * 256 + threadIdx.x;
  if (t < PR0) {
    int which = (t >= H1 * C1) ? 1 : 0;
    int r = t - which * H1 * C1;
    int h = r / C1, k = r - h * C1;
    const float* a = which ? a_dst : a_src;
    float s = 0.f;
    for (int c = 0; c < C1; c++) s += W1[(size_t)k * F1 + h * C1 + c] * a[h * C1 + c];
    (which ? Vd : Vs)[h * C1 + k] = s;
    return;
  }
  t -= PR0;
  if (t < PR1) {
    int h = t / (80 * K1PAD);
    int rem = t - h * 80 * K1PAD;
    int c = rem / K1PAD, k = rem - c * K1PAD;
    float v = (c < C1 && k < C1) ? W1[(size_t)k * F1 + h * C1 + c] : 0.f;
    W1t[t] = f2b(v);
    return;
  }
  t -= PR1;
  if (t < PR2) {
    int c = t / K2PAD, k = t - c * K2PAD;
    float v = (c < C2 && k < F1) ? W2[(size_t)k * C2 + c] : 0.f;
    W2t[t] = f2b(v);
    return;
  }
  t -= PR2;
  if (t < PR4) {
    int n = t / 40, c2 = t - n * 40;
    ushort2 o;
    if (c2 < 39) { o.x = f2h(x[(size_t)n * C1 + 2 * c2]); o.y = f2h(x[(size_t)n * C1 + 2 * c2 + 1]); }
    else         { o.x = 0; o.y = 0; }
    *(ushort2*)(xhf + (size_t)n * 80 + 2 * c2) = o;
  }
}

/* ---------------- fused scan (block 0) + layer-1 logits (blocks 1..) -------------- */

__global__ __launch_bounds__(1024) void k_scanalpha(const int* __restrict__ cnt,
                                                    int* __restrict__ offs,
                                                    const float* __restrict__ x,
                                                    const float* __restrict__ Vs,
                                                    const float* __restrict__ Vd,
                                                    float* __restrict__ asb,
                                                    float* __restrict__ adb) {
  if (blockIdx.x == 0) {
    const int PER = 20;
    int t = threadIdx.x;
    int lane = t & 63, wv = t >> 6;
    int base = t * PER;
    int raw[PER];
    const int4* c4 = (const int4*)(cnt + base);
#pragma unroll
    for (int q = 0; q < 5; q++) {
      int4 v = c4[q];
      raw[4 * q] = v.x; raw[4 * q + 1] = v.y; raw[4 * q + 2] = v.z; raw[4 * q + 3] = v.w;
    }
    int loc[PER];
    int run = 0;
#pragma unroll
    for (int k = 0; k < PER; k++) {
      int idx = base + k;
      run += (idx < N_NODES) ? raw[k] : 0;
      loc[k] = run;
    }
    int total = run;
    int sc = total;
#pragma unroll
    for (int o = 1; o < 64; o <<= 1) {
      int u = __shfl_up(sc, o);
      if (lane >= o) sc += u;
    }
    __shared__ int ws[16];
    if (lane == 63) ws[wv] = sc;
    __syncthreads();
    if (t == 0) {
      int r = 0;
#pragma unroll
      for (int i = 0; i < 16; i++) { int v = ws[i]; ws[i] = r; r += v; }
    }
    __syncthreads();
    int excl = ws[wv] + sc - total;
#pragma unroll
    for (int k = 0; k < PER; k++) {
      int idx = base + k;
      if (idx < N_NODES) offs[idx + 1] = excl + loc[k];
    }
    if (t == 0) offs[0] = 0;
    return;
  }

  /* alpha1x part */
  __shared__ float sVs[H1 * C1], sVd[H1 * C1];
  for (int i = threadIdx.x; i < H1 * C1; i += 1024) { sVs[i] = Vs[i]; sVd[i] = Vd[i]; }
  __syncthreads();
  int t = (blockIdx.x - 1) * 1024 + threadIdx.x;
  if (t >= N_NODES * H1) return;
  int n = t / H1, h = t - n * H1;
  const float2* row = (const float2*)(x + (size_t)n * C1);
  const float2* vs2 = (const float2*)(sVs + h * C1);
  const float2* vd2 = (const float2*)(sVd + h * C1);
  float s0 = 0.f, s1 = 0.f;
#pragma unroll 13
  for (int i = 0; i < C1 / 2; i++) {
    float2 v = row[i];
    float2 a = vs2[i];
    float2 b = vd2[i];
    s0 += v.x * a.x + v.y * a.y;
    s1 += v.x * b.x + v.y * b.y;
  }
  asb[(size_t)n * HP + h] = s0;
  adb[(size_t)n * HP + h] = s1;
}

/* ---------------- fused scatter + edge weights: srcs[pos], ex1t[h][pos] ------------ */

__global__ void k_scatterex(const int* __restrict__ ei, const int* __restrict__ offs,
                            int* __restrict__ cursor,
                            const float* __restrict__ asb, const float* __restrict__ adb,
                            int* __restrict__ srcs, ushort_t* __restrict__ ex1t) {
  int e = blockIdx.x * blockDim.x + threadIdx.x;
  if (e >= E_TOT) return;
  int src, dst;
  if (e < N_EDGES) { src = ei[e]; dst = ei[N_EDGES + e]; }
  else             { src = dst = e - N_EDGES; }
  int pos = offs[dst] + atomicAdd(&cursor[dst], 1);
  srcs[pos] = src;
  const float* pa = asb + (size_t)src * HP;
  const float* pd = adb + (size_t)dst * HP;
  float4 a0 = *(const float4*)pa, a1 = *(const float4*)(pa + 4);
  float2 a2 = *(const float2*)(pa + 8);
  float4 d0 = *(const float4*)pd, d1 = *(const float4*)(pd + 4);
  float2 d2 = *(const float2*)(pd + 8);
  float r[10];
  r[0] = __expf(lrelu(a0.x + d0.x)); r[1] = __expf(lrelu(a0.y + d0.y));
  r[2] = __expf(lrelu(a0.z + d0.z)); r[3] = __expf(lrelu(a0.w + d0.w));
  r[4] = __expf(lrelu(a1.x + d1.x)); r[5] = __expf(lrelu(a1.y + d1.y));
  r[6] = __expf(lrelu(a1.z + d1.z)); r[7] = __expf(lrelu(a1.w + d1.w));
  r[8] = __expf(lrelu(a2.x + d2.x)); r[9] = __expf(lrelu(a2.y + d2.y));
#pragma unroll
  for (int h = 0; h < H1; h++) ex1t[(size_t)h * E_TOT + pos] = f2h(r[h]);
}

/* ---------------- layer-1 aggregation: wave per dst, fp16 dot2, fused denom ------- */

__global__ __launch_bounds__(256) void k_aggv5(const ushort_t* __restrict__ xhf,
                                               const ushort_t* __restrict__ ex1t,
                                               const int* __restrict__ offs,
                                               const int* __restrict__ srcs,
                                               ushort_t* __restrict__ xb) {
  int wid = (blockIdx.x * 256 + threadIdx.x) >> 6;
  int lane = threadIdx.x & 63;
  if (wid >= N_NODES) return;
  int n = wid;
  int beg = __builtin_amdgcn_readfirstlane(offs[n]);
  int end = __builtin_amdgcn_readfirstlane(offs[n + 1]);

  float acc0[H1] = {}, acc1[H1] = {}, sum[H1] = {};
  const unsigned int ONES = 0x3C003C00u;   /* (fp16 1.0, fp16 1.0) */

  for (int e0 = beg & ~1; e0 < end; e0 += 2) {
    unsigned int m = 0xFFFFFFFFu;
    if (e0 < beg) m &= 0xFFFF0000u;          /* slot0 before this node's range */
    if (e0 + 1 >= end) m &= 0x0000FFFFu;     /* slot1 past this node's range  */
    int s0 = srcs[e0], s1 = srcs[e0 + 1];    /* e0 even <= E_TOT-2: in bounds */
    unsigned int w[H1];
#pragma unroll
    for (int h = 0; h < H1; h++)
      w[h] = *(const unsigned int*)(ex1t + (size_t)h * E_TOT + e0);   /* 4B aligned */
    unsigned int xv0 = 0, xv1 = 0;
    if (lane < 39) {
      xv0 = *(const unsigned int*)(xhf + (size_t)s0 * 80 + 2 * lane);
      xv1 = *(const unsigned int*)(xhf + (size_t)s1 * 80 + 2 * lane);
    }
    unsigned int xA = __builtin_amdgcn_perm(xv1, xv0, 0x05040100u) & m;  /* (s0.lo, s1.lo) */
    unsigned int xB = __builtin_amdgcn_perm(xv1, xv0, 0x07060302u) & m;  /* (s0.hi, s1.hi) */
    unsigned int on = ONES & m;
#pragma unroll
    for (int h = 0; h < H1; h++) {
      acc0[h] = dot2h(w[h], xA, acc0[h]);
      acc1[h] = dot2h(w[h], xB, acc1[h]);
      sum[h]  = dot2h(w[h], on, sum[h]);
    }
  }

  if (lane < 48) {
    int colu = (lane < 39) ? 2 * lane : C1 + 2 * (lane - 39);   /* pad cols 78..95 */
#pragma unroll
    for (int h = 0; h < H1; h++) {
      float iv = 1.f / (sum[h] + 1e-16f);
      ushort2 o;
      if (lane < 39) { o.x = f2b(acc0[h] * iv); o.y = f2b(acc1[h] * iv); }
      else           { o.x = 0; o.y = 0; }
      *(ushort2*)(xb + ((size_t)h * N_NODES + n) * K1PAD + colu) = o;
    }
  }
}

/* ---------------- fused layer-1 GEMM + ELU + layer-2 GEMM + alpha2 ----------------
   One block owns 64 node-rows. Phase 1: per head, xb-tile @ W1t[h] -> ELU -> ha in
   LDS [64][808]. Phase 2: ha_LDS @ W2t (25 K-steps). Epilogue: z2b bf16 + as2/ad2. */

__global__ __launch_bounds__(256) void k_fused12(const ushort_t* __restrict__ xb,
                                                 const ushort_t* __restrict__ W1t,
                                                 const float* __restrict__ b1,
                                                 const ushort_t* __restrict__ W2t,
                                                 const float* __restrict__ a_src,
                                                 const float* __restrict__ a_dst,
                                                 ushort_t* __restrict__ z2b,
                                                 float* __restrict__ as2,
                                                 float* __restrict__ ad2) {
  __shared__ ushort_t sHA[64 * HAP];   /* 103.4 KB */
  __shared__ ushort_t sS[80 * AP1];    /* 16.6 KB: W1 stage (p1) / W2 chunk (p2) */
  __shared__ ushort_t sXB[64 * AP1];   /* 13.3 KB */
  int m0 = blockIdx.x * 64;
  int tid = threadIdx.x;
  int w = tid >> 6, l = tid & 63;
  int rb = l & 15, g = l >> 4;

  /* zero ha pad columns [780, 808) */
  for (int i = tid; i < 64 * 28; i += 256) {
    int r = i / 28, c = i - r * 28;
    sHA[r * HAP + F1 + c] = 0;
  }

  /* ---- phase 1 ---- */
  for (int h = 0; h < H1; h++) {
    __syncthreads();   /* protect sXB/sS reuse (and pad-zero on first iter) */
    for (int i = tid; i < 64 * 12; i += 256) {
      int r = i / 12, cx = i - r * 12;
      uint4 v = make_uint4(0, 0, 0, 0);
      int m = m0 + r;
      if (m < N_NODES) v = *(const uint4*)(xb + ((size_t)h * N_NODES + m) * K1PAD + cx * 8);
      *(uint4*)(sXB + r * AP1 + cx * 8) = v;
    }
    for (int i = tid; i < 80 * 12; i += 256) {
      int c = i / 12, cx = i - c * 12;
      uint4 v = *(const uint4*)(W1t + ((size_t)h * 80 + c) * K1PAD + cx * 8);
      *(uint4*)(sS + c * AP1 + cx * 8) = v;
    }
    __syncthreads();
    f32x4 acc[5] = {};
    const ushort_t* pa = sXB + (w * 16 + rb) * AP1 + g * 8;
#pragma unroll
    for (int k0 = 0; k0 < K1PAD; k0 += 32) {
      bf16x8 a = *(const bf16x8*)(pa + k0);
#pragma unroll
      for (int ct = 0; ct < 5; ct++) {
        bf16x8 b = *(const bf16x8*)(sS + (ct * 16 + rb) * AP1 + k0 + g * 8);
        acc[ct] = __builtin_amdgcn_mfma_f32_16x16x32_bf16(a, b, acc[ct], 0, 0, 0);
      }
    }
    int mrow_l = w * 16 + g * 4;
#pragma unroll
    for (int ct = 0; ct < 5; ct++) {
      int col = ct * 16 + rb;
      if (col >= C1) continue;
      float bias = b1[h * C1 + col];
#pragma unroll
      for (int r = 0; r < 4; r++) {
        float v = acc[ct][r] + bias;
        v = (v > 0.f) ? v : (__expf(v) - 1.f);
        sHA[(mrow_l + r) * HAP + h * C1 + col] = f2b(v);
      }
    }
  }
  __syncthreads();

  /* ---- phase 2 ---- */
  f32x4 acc2[7] = {};
  for (int ks = 0; ks < 25; ks++) {
    if (ks) __syncthreads();   /* protect sS reuse across K-steps */
    for (int i = tid; i < 112 * 4; i += 256) {
      int c = i >> 2, cx = i & 3;
      uint4 v = *(const uint4*)(W2t + (size_t)c * K2PAD + ks * 32 + cx * 8);
      *(uint4*)(sS + c * AP2 + cx * 8) = v;
    }
    __syncthreads();
    bf16x8 a = *(const bf16x8*)(sHA + (w * 16 + rb) * HAP + ks * 32 + g * 8);
#pragma unroll
    for (int ct = 0; ct < 7; ct++) {
      bf16x8 b = *(const bf16x8*)(sS + (ct * 16 + rb) * AP2 + g * 8);
      acc2[ct] = __builtin_amdgcn_mfma_f32_16x16x32_bf16(a, b, acc2[ct], 0, 0, 0);
    }
  }

  /* ---- epilogue: z2b + alpha2 (16-lane shfl reduce per row) ---- */
  float asv[7], adv[7];
#pragma unroll
  for (int ct = 0; ct < 7; ct++) {
    int col = ct * 16 + rb;
    bool cv = col < C2;
    asv[ct] = cv ? a_src[cv ? col : 0] : 0.f;
    adv[ct] = cv ? a_dst[cv ? col : 0] : 0.f;
  }
#pragma unroll
  for (int r = 0; r < 4; r++) {
    int m = m0 + w * 16 + g * 4 + r;
    bool mv = m < N_NODES;
    float ps = 0.f, pd = 0.f;
#pragma unroll
    for (int ct = 0; ct < 7; ct++) {
      int col = ct * 16 + rb;
      float z = acc2[ct][r];
      if (col < C2 && mv) z2b[(size_t)m * C2 + col] = f2b(z);
      ps += z * asv[ct];
      pd += z * adv[ct];
    }
#pragma unroll
    for (int o = 8; o; o >>= 1) { ps += __shfl_xor(ps, o); pd += __shfl_xor(pd, o); }
    if (mv && rb == 0) { as2[m] = ps; ad2[m] = pd; }
  }
}

/* ---------------- layer-2 aggregation + inline edge-exp + bias + ReLU + pool ------ */

__global__ __launch_bounds__(256) void k_gat2v4(const ushort_t* __restrict__ z2b,
                                                const float* __restrict__ as2,
                                                const float* __restrict__ ad2,
                                                const int* __restrict__ offs,
                                                const int* __restrict__ srcs,
                                                const float* __restrict__ b2,
                                                const int* __restrict__ batch,
                                                unsigned int* __restrict__ pool) {
  int wid = (blockIdx.x * 256 + threadIdx.x) >> 6;
  int lane = threadIdx.x & 63;
  if (wid >= N_NODES) return;
  int n = wid;
  int beg = offs[n], deg = offs[n + 1] - beg;
  float adn = ad2[n];
  const unsigned int* zrow = (const unsigned int*)z2b;

  float acc0 = 0.f, acc1 = 0.f, sum = 0.f;

  for (int j = 0; j < deg; j += 8) {
    int sj[8]; bool vj[8];
#pragma unroll
    for (int q = 0; q < 8; q++) {
      int jj = j + q;
      vj[q] = jj < deg;
      sj[q] = srcs[vj[q] ? beg + jj : beg];
    }
    float p[8];
#pragma unroll
    for (int q = 0; q < 8; q++) {
      float pv = __expf(lrelu(as2[sj[q]] + adn));
      p[q] = vj[q] ? pv : 0.f;
    }
    unsigned int z[8] = {0, 0, 0, 0, 0, 0, 0, 0};
    if (lane < C2 / 2) {
#pragma unroll
      for (int q = 0; q < 8; q++) z[q] = zrow[(size_t)sj[q] * (C2 / 2) + lane];
    }
#pragma unroll
    for (int q = 0; q < 8; q++) {
      acc0 += p[q] * bf_lo(z[q]);
      acc1 += p[q] * bf_hi(z[q]);
      sum += p[q];
    }
  }

  if (lane < C2 / 2) {
    float iv = 1.f / (sum + 1e-16f);
    float v0 = fmaxf(acc0 * iv + b2[2 * lane], 0.f);
    float v1 = fmaxf(acc1 * iv + b2[2 * lane + 1], 0.f);
    int g = batch[n];
    atomicMax(&pool[g * C2 + 2 * lane], __float_as_uint(v0));
    atomicMax(&pool[g * C2 + 2 * lane + 1], __float_as_uint(v1));
  }
}

/* ---------------- head: out = relu(pool @ Wg + bg) ---------------- */

__global__ __launch_bounds__(128) void k_head(const float* __restrict__ pool,
                                              const float* __restrict__ Wg,
                                              const float* __restrict__ bg,
                                              float* __restrict__ out) {
  __shared__ float row[C2];
  int g = blockIdx.x;
  if (threadIdx.x < C2) row[threadIdx.x] = pool[g * C2 + threadIdx.x];
  __syncthreads();
  int c = threadIdx.x;
  if (c < C2) {
    float acc = bg[c];
    for (int k = 0; k < C2; k++) acc += row[k] * Wg[k * C2 + c];
    out[g * C2 + c] = fmaxf(acc, 0.f);
  }
}

/* ---------------- launch ---------------- */

extern "C" void kernel_launch(void* const* d_in, const int* in_sizes, int n_in,
                              void* d_out, int out_size, void* d_ws, size_t ws_size,
                              hipStream_t stream) {
  const float* x      = (const float*)d_in[0];
  const int*   ei     = (const int*)d_in[1];
  const int*   batch  = (const int*)d_in[2];
  const float* W1     = (const float*)d_in[4];
  const float* a_src1 = (const float*)d_in[5];
  const float* a_dst1 = (const float*)d_in[6];
  const float* b1     = (const float*)d_in[7];
  const float* W2     = (const float*)d_in[8];
  const float* a_src2 = (const float*)d_in[9];
  const float* a_dst2 = (const float*)d_in[10];
  const float* b2     = (const float*)d_in[11];
  const float* Wg     = (const float*)d_in[12];
  const float* bg     = (const float*)d_in[13];
  float* out = (float*)d_out;

  char* w = (char*)d_ws;
  size_t off = 0;
  auto alloc = [&](size_t bytes) -> void* {
    void* p = w + off;
    off += (bytes + 255) & ~(size_t)255;
    return p;
  };

  ushort_t* xb   = (ushort_t*)alloc((size_t)H1 * N_NODES * K1PAD * 2);  /* 38.4 MB */
  float* asb     = (float*)alloc((size_t)N_NODES * HP * 4);             /* 0.96 MB */
  float* adb     = (float*)alloc((size_t)N_NODES * HP * 4);
  ushort_t* ex1t = (ushort_t*)alloc((size_t)H1 * E_TOT * 2);            /* 6.8 MB */
  ushort_t* xhf  = (ushort_t*)alloc((size_t)N_NODES * 80 * 2);          /* 3.2 MB */
  float* Vs      = (float*)alloc((size_t)H1 * C1 * 4);
  float* Vd      = (float*)alloc((size_t)H1 * C1 * 4);
  ushort_t* W1t  = (ushort_t*)alloc((size_t)H1 * 80 * K1PAD * 2);
  ushort_t* W2t  = (ushort_t*)alloc((size_t)112 * K2PAD * 2);
  ushort_t* z2b  = (ushort_t*)alloc((size_t)N_NODES * C2 * 2);          /* 4 MB */
  float* as2     = (float*)alloc((size_t)N_NODES * 4);
  float* ad2     = (float*)alloc((size_t)N_NODES * 4);
  /* cnt / cursor / pool: one contiguous zero region */
  int* cnt           = (int*)alloc((size_t)N_NODES * 4);
  int* cursor        = (int*)alloc((size_t)N_NODES * 4);
  unsigned int* pool = (unsigned int*)alloc((size_t)N_GRAPHS * C2 * 4);
  size_t zspan = (size_t)((char*)(pool + (size_t)N_GRAPHS * C2) - (char*)cnt);
  int* offs   = (int*)alloc((size_t)(N_NODES + 1) * 4);
  int* srcs   = (int*)alloc((size_t)E_TOT * 4);

  hipMemsetAsync(cnt, 0, zspan, stream);

  k_cntprep<<<NB_CNT + NB_PREP, 256, 0, stream>>>(ei, W1, a_src1, a_dst1, W2, x,
                                                  cnt, Vs, Vd, W1t, W2t, xhf);
  k_scanalpha<<<1 + (N_NODES * H1 + 1023) / 1024, 1024, 0, stream>>>(cnt, offs, x, Vs, Vd,
                                                                     asb, adb);
  k_scatterex<<<(E_TOT + 255) / 256, 256, 0, stream>>>(ei, offs, cursor, asb, adb,
                                                       srcs, ex1t);
  k_aggv5<<<(N_NODES + 3) / 4, 256, 0, stream>>>(xhf, ex1t, offs, srcs, xb);
  k_fused12<<<(N_NODES + 63) / 64, 256, 0, stream>>>(xb, W1t, b1, W2t, a_src2, a_dst2,
                                                     z2b, as2, ad2);
  k_gat2v4<<<(N_NODES + 3) / 4, 256, 0, stream>>>(z2b, as2, ad2, offs, srcs, b2, batch, pool);
  k_head<<<N_GRAPHS, 128, 0, stream>>>((const float*)pool, Wg, bg, out);
}